// Round 1
// baseline (282.947 us; speedup 1.0000x reference)
//
#include <hip/hip_runtime.h>

#define BB 8
#define SS 1024
#define HH 256
#define CC 4
#define NQ 1024  // H*C

typedef unsigned short u16;
typedef unsigned int u32;
typedef __attribute__((ext_vector_type(8))) __bf16 bf16x8;
typedef __attribute__((ext_vector_type(4))) float f32x4;
typedef __attribute__((ext_vector_type(4))) u32 u32x4;

__device__ __forceinline__ u16 f2bf(float f) {
    u32 u = __float_as_uint(f);
    u32 r = (u + 0x7FFFu + ((u >> 16) & 1u)) >> 16;
    return (u16)r;
}

__device__ __forceinline__ bf16x8 loadfrag(const u16* p) {
    u32x4 raw = *(const u32x4*)p;
    return __builtin_bit_cast(bf16x8, raw);
}

// ---------- prep kernels ----------
__global__ void k0_castx(const float* __restrict__ x, u16* __restrict__ xbf) {
    int i = blockIdx.x * 256 + threadIdx.x;  // 2,097,152 elems
    xbf[i] = f2bf(x[i]);
}

__global__ void k0_transw(const float* __restrict__ Wq, const float* __restrict__ Wk,
                          u16* __restrict__ Wt) {
    int i = blockIdx.x * 256 + threadIdx.x;  // 524,288 elems
    int n = i >> 8, k = i & 255;
    float v = (n < NQ) ? Wq[k * NQ + n] : Wk[k * NQ + (n - NQ)];
    Wt[i] = f2bf(v);  // Wt[n][k]
}

__global__ void k0_trig(float2* __restrict__ trig) {
    int i = blockIdx.x * 256 + threadIdx.x;  // 32768 = 256 pos x 128 freq
    int pos = i >> 7, f = i & 127;
    float freq = __expf(-(float)f * 0.07195578515529633f);  // ln(10000)/128
    float ang = (float)pos * freq;
    float s, c;
    sincosf(ang, &s, &c);
    trig[i] = make_float2(c, s);
}

// ---------- projection GEMM + bias + RoPE epilogue ----------
// P(m,n) = sum_k xbf[m][k] * Wt[n][k];  m in [0,8192), n in [0,2048)
// n<1024 -> q (write qpos/qneg), else k (write kpos/kneg), layout (B,C,S,H)
__global__ void __launch_bounds__(256) k1_proj(
    const u16* __restrict__ xbf, const u16* __restrict__ Wt,
    const float* __restrict__ bq, const float* __restrict__ bk,
    const int* __restrict__ tok, const float2* __restrict__ trig,
    u16* __restrict__ qpos, u16* __restrict__ qneg,
    u16* __restrict__ kpos, u16* __restrict__ kneg) {
    int wg = blockIdx.x;          // 4096 = 128 (m tiles) x 32 (n tiles)
    int mt = wg >> 5, nt = wg & 31;
    int m0 = mt * 64, n0 = nt * 64;
    int w = threadIdx.x >> 6, l = threadIdx.x & 63;
    int lin = (l & 15) * HH + ((l >> 4) * 8);
    int ar = m0 + w * 16;

    const u16* pa = xbf + (size_t)ar * HH + lin;
    f32x4 acc[4] = {};
#pragma unroll
    for (int kk = 0; kk < 8; ++kk) {
        bf16x8 a = loadfrag(pa + kk * 32);
#pragma unroll
        for (int ns = 0; ns < 4; ++ns) {
            bf16x8 bfr = loadfrag(Wt + (size_t)(n0 + ns * 16) * HH + lin + kk * 32);
            acc[ns] = __builtin_amdgcn_mfma_f32_16x16x32_bf16(a, bfr, acc[ns], 0, 0, 0);
        }
    }
    // epilogue: bias + rope (pairs are adjacent cols -> adjacent lanes)
#pragma unroll
    for (int ns = 0; ns < 4; ++ns) {
        int n = n0 + ns * 16 + (l & 15);
        bool isq = n < NQ;
        int nc = n & (NQ - 1);
        float bias = isq ? bq[nc] : bk[nc];
        int c = nc >> 8, h = nc & 255, fi = h >> 1;
#pragma unroll
        for (int r = 0; r < 4; ++r) {
            int m = ar + (l >> 4) * 4 + r;
            float val = acc[ns][r] + bias;
            float other = __shfl_xor(val, 1);
            int pos = tok[m];
            float2 cs = trig[pos * 128 + fi];
            float rp, rn;
            if ((l & 1) == 0) {  // even col: re = v0*cos - v1*sin ; neg: +sin
                rp = val * cs.x - other * cs.y;
                rn = val * cs.x + other * cs.y;
            } else {             // odd col: im = v0*sin + v1*cos ; neg: -v0*sin + v1*cos
                rp = other * cs.y + val * cs.x;
                rn = -other * cs.y + val * cs.x;
            }
            int b = m >> 10, s = m & 1023;
            size_t oidx = ((size_t)((b << 2) | c) * SS + s) * HH + h;
            if (isq) {
                qpos[oidx] = f2bf(rp);
                qneg[oidx] = f2bf(rn);
            } else {
                kpos[oidx] = f2bf(rp);
                kneg[oidx] = f2bf(rn);
            }
        }
    }
}

// ---------- main GEMM: 3 accumulators + thread_id select ----------
// per (b,c): out[m][n] = sel( qpos[m].kpos[n], qneg[m].kpos[n], qpos[m].kneg[n] )
__global__ void __launch_bounds__(256) k2_gemm(
    const u16* __restrict__ qpos, const u16* __restrict__ qneg,
    const u16* __restrict__ kpos, const u16* __restrict__ kneg,
    const int* __restrict__ thread_id, float* __restrict__ out) {
    int wg = blockIdx.x;                     // 4096
    int swz = (wg & 7) * 512 + (wg >> 3);    // XCD swizzle (4096 % 8 == 0, bijective)
    int bc = swz >> 7;                       // 32 (b,c) pairs, 128 blocks each
    int t = swz & 127;
    int tm = t >> 4, tn = t & 15;            // 8 x 16 tiles of 128x64
    int m0 = tm * 128, n0 = tn * 64;
    int w = threadIdx.x >> 6, l = threadIdx.x & 63;

    size_t base = (size_t)bc * (SS * HH);
    int lin = (l & 15) * HH + ((l >> 4) * 8);
    int ar0 = m0 + w * 32;

    const u16* pqp[2]; const u16* pqn[2]; const u16* pkp[4]; const u16* pkn[4];
#pragma unroll
    for (int mi = 0; mi < 2; ++mi) {
        size_t o = base + (size_t)(ar0 + mi * 16) * HH + lin;
        pqp[mi] = qpos + o;
        pqn[mi] = qneg + o;
    }
#pragma unroll
    for (int ns = 0; ns < 4; ++ns) {
        size_t o = base + (size_t)(n0 + ns * 16) * HH + lin;
        pkp[ns] = kpos + o;
        pkn[ns] = kneg + o;
    }

    f32x4 a1[2][4] = {}, a2[2][4] = {}, a3[2][4] = {};
#pragma unroll
    for (int kk = 0; kk < 8; ++kk) {
        bf16x8 qpF[2], qnF[2], kpF[4], knF[4];
#pragma unroll
        for (int mi = 0; mi < 2; ++mi) {
            qpF[mi] = loadfrag(pqp[mi] + kk * 32);
            qnF[mi] = loadfrag(pqn[mi] + kk * 32);
        }
#pragma unroll
        for (int ns = 0; ns < 4; ++ns) {
            kpF[ns] = loadfrag(pkp[ns] + kk * 32);
            knF[ns] = loadfrag(pkn[ns] + kk * 32);
        }
#pragma unroll
        for (int mi = 0; mi < 2; ++mi)
#pragma unroll
            for (int ns = 0; ns < 4; ++ns) {
                a1[mi][ns] = __builtin_amdgcn_mfma_f32_16x16x32_bf16(qpF[mi], kpF[ns], a1[mi][ns], 0, 0, 0);
                a2[mi][ns] = __builtin_amdgcn_mfma_f32_16x16x32_bf16(qnF[mi], kpF[ns], a2[mi][ns], 0, 0, 0);
                a3[mi][ns] = __builtin_amdgcn_mfma_f32_16x16x32_bf16(qpF[mi], knF[ns], a3[mi][ns], 0, 0, 0);
            }
    }

    // epilogue: select by thread_id and store
    int b = bc >> 2;
    const int* tid = thread_id + b * SS;
    int tj[4], ti_[2][4];
#pragma unroll
    for (int ns = 0; ns < 4; ++ns) tj[ns] = tid[n0 + ns * 16 + (l & 15)];
#pragma unroll
    for (int mi = 0; mi < 2; ++mi)
#pragma unroll
        for (int r = 0; r < 4; ++r) ti_[mi][r] = tid[ar0 + mi * 16 + (l >> 4) * 4 + r];

    float* ob = out + (size_t)bc * ((size_t)SS * SS);
#pragma unroll
    for (int mi = 0; mi < 2; ++mi)
#pragma unroll
        for (int ns = 0; ns < 4; ++ns)
#pragma unroll
            for (int r = 0; r < 4; ++r) {
                int m = ar0 + mi * 16 + (l >> 4) * 4 + r;
                int n = n0 + ns * 16 + (l & 15);
                int ti = ti_[mi][r], tjj = tj[ns];
                float v = (ti > 0 && ti < tjj) ? a2[mi][ns][r]
                         : ((tjj > 0 && ti > tjj) ? a3[mi][ns][r] : a1[mi][ns][r]);
                ob[(size_t)m * SS + n] = v;
            }
}

extern "C" void kernel_launch(void* const* d_in, const int* in_sizes, int n_in,
                              void* d_out, int out_size, void* d_ws, size_t ws_size,
                              hipStream_t stream) {
    const float* x  = (const float*)d_in[0];
    const float* Wq = (const float*)d_in[1];
    const float* bq = (const float*)d_in[2];
    const float* Wk = (const float*)d_in[3];
    const float* bk = (const float*)d_in[4];
    const int* tok  = (const int*)d_in[5];
    const int* tid  = (const int*)d_in[6];
    float* out = (float*)d_out;

    char* ws = (char*)d_ws;
    const size_t MB = 1u << 20;
    u16* qpos = (u16*)(ws);
    u16* qneg = (u16*)(ws + 16 * MB);
    u16* kpos = (u16*)(ws + 32 * MB);
    u16* kneg = (u16*)(ws + 48 * MB);
    u16* xbf  = (u16*)(ws + 64 * MB);
    u16* Wt   = (u16*)(ws + 68 * MB);
    float2* trig = (float2*)(ws + 69 * MB);

    k0_castx<<<8192, 256, 0, stream>>>(x, xbf);
    k0_transw<<<2048, 256, 0, stream>>>(Wq, Wk, Wt);
    k0_trig<<<128, 256, 0, stream>>>(trig);
    k1_proj<<<4096, 256, 0, stream>>>(xbf, Wt, bq, bk, tok, trig, qpos, qneg, kpos, kneg);
    k2_gemm<<<4096, 256, 0, stream>>>(qpos, qneg, kpos, kneg, tid, out);
}

// Round 2
// 269.546 us; speedup vs baseline: 1.0497x; 1.0497x over previous
//
#include <hip/hip_runtime.h>

#define BB 8
#define SS 1024
#define HH 256
#define CC 4
#define NQ 1024  // H*C

typedef unsigned short u16;
typedef unsigned int u32;
typedef __attribute__((ext_vector_type(8))) __bf16 bf16x8;
typedef __attribute__((ext_vector_type(4))) float f32x4;
typedef __attribute__((ext_vector_type(4))) u32 u32x4;

__device__ __forceinline__ u16 f2bf(float f) {
    u32 u = __float_as_uint(f);
    u32 r = (u + 0x7FFFu + ((u >> 16) & 1u)) >> 16;
    return (u16)r;
}

__device__ __forceinline__ bf16x8 loadfrag(const u16* p) {
    u32x4 raw = *(const u32x4*)p;
    return __builtin_bit_cast(bf16x8, raw);
}

// ---------- prep kernels ----------
__global__ void k0_castx(const float* __restrict__ x, u16* __restrict__ xbf) {
    int i = blockIdx.x * 256 + threadIdx.x;  // 2,097,152 elems
    xbf[i] = f2bf(x[i]);
}

__global__ void k0_transw(const float* __restrict__ Wq, const float* __restrict__ Wk,
                          u16* __restrict__ Wt) {
    int i = blockIdx.x * 256 + threadIdx.x;  // 524,288 elems
    int n = i >> 8, k = i & 255;
    float v = (n < NQ) ? Wq[k * NQ + n] : Wk[k * NQ + (n - NQ)];
    Wt[i] = f2bf(v);  // Wt[n][k]
}

__global__ void k0_trig(float2* __restrict__ trig) {
    int i = blockIdx.x * 256 + threadIdx.x;  // 32768 = 256 pos x 128 freq
    int pos = i >> 7, f = i & 127;
    float freq = __expf(-(float)f * 0.07195578515529633f);  // ln(10000)/128
    float ang = (float)pos * freq;
    float s, c;
    sincosf(ang, &s, &c);
    trig[i] = make_float2(c, s);
}

// ---------- projection GEMM + bias + RoPE epilogue ----------
__global__ void __launch_bounds__(256) k1_proj(
    const u16* __restrict__ xbf, const u16* __restrict__ Wt,
    const float* __restrict__ bq, const float* __restrict__ bk,
    const int* __restrict__ tok, const float2* __restrict__ trig,
    u16* __restrict__ qpos, u16* __restrict__ qneg,
    u16* __restrict__ kpos, u16* __restrict__ kneg) {
    int wg = blockIdx.x;          // 4096 = 128 (m tiles) x 32 (n tiles)
    int mt = wg >> 5, nt = wg & 31;
    int m0 = mt * 64, n0 = nt * 64;
    int w = threadIdx.x >> 6, l = threadIdx.x & 63;
    int lin = (l & 15) * HH + ((l >> 4) * 8);
    int ar = m0 + w * 16;

    const u16* pa = xbf + (size_t)ar * HH + lin;
    f32x4 acc[4] = {};
#pragma unroll
    for (int kk = 0; kk < 8; ++kk) {
        bf16x8 a = loadfrag(pa + kk * 32);
#pragma unroll
        for (int ns = 0; ns < 4; ++ns) {
            bf16x8 bfr = loadfrag(Wt + (size_t)(n0 + ns * 16) * HH + lin + kk * 32);
            acc[ns] = __builtin_amdgcn_mfma_f32_16x16x32_bf16(a, bfr, acc[ns], 0, 0, 0);
        }
    }
#pragma unroll
    for (int ns = 0; ns < 4; ++ns) {
        int n = n0 + ns * 16 + (l & 15);
        bool isq = n < NQ;
        int nc = n & (NQ - 1);
        float bias = isq ? bq[nc] : bk[nc];
        int c = nc >> 8, h = nc & 255, fi = h >> 1;
#pragma unroll
        for (int r = 0; r < 4; ++r) {
            int m = ar + (l >> 4) * 4 + r;
            float val = acc[ns][r] + bias;
            float other = __shfl_xor(val, 1);
            int pos = tok[m];
            float2 cs = trig[pos * 128 + fi];
            float rp, rn;
            if ((l & 1) == 0) {
                rp = val * cs.x - other * cs.y;
                rn = val * cs.x + other * cs.y;
            } else {
                rp = other * cs.y + val * cs.x;
                rn = -other * cs.y + val * cs.x;
            }
            int b = m >> 10, s = m & 1023;
            size_t oidx = ((size_t)((b << 2) | c) * SS + s) * HH + h;
            if (isq) {
                qpos[oidx] = f2bf(rp);
                qneg[oidx] = f2bf(rn);
            } else {
                kpos[oidx] = f2bf(rp);
                kneg[oidx] = f2bf(rn);
            }
        }
    }
}

// ---------- main GEMM, split into pure-tile and mixed-tile kernels ----------
// Tile classification from sorted thread_id:
//   ti range = [tid[m0], tid[m0+127]], tj range = [tid[n0], tid[n0+63]]
//   pure2: all (m,n) satisfy 0<ti<tj   -> out = l2 = qneg.kpos
//   pure3: all satisfy tj>0 && ti>tj   -> out = l3 = qpos.kneg
//   pure1: no element satisfies either -> out = l1 = qpos.kpos
__global__ void __launch_bounds__(256, 4) k2_pure(
    const u16* __restrict__ qpos, const u16* __restrict__ qneg,
    const u16* __restrict__ kpos, const u16* __restrict__ kneg,
    const int* __restrict__ thread_id, float* __restrict__ out) {
    int wg = blockIdx.x;                     // 4096
    int swz = (wg & 7) * 512 + (wg >> 3);    // XCD swizzle
    int bc = swz >> 7;
    int t = swz & 127;
    int m0 = (t >> 4) * 128, n0 = (t & 15) * 64;
    int b = bc >> 2;
    const int* tb = thread_id + b * SS;
    int ti0 = tb[m0], ti1 = tb[m0 + 127], tj0 = tb[n0], tj1 = tb[n0 + 63];
    bool pure2 = (ti0 > 0) & (ti1 < tj0);
    bool pure3 = (tj0 > 0) & (ti0 > tj1);
    bool pure1 = (ti1 == 0) | (tj1 == 0) | ((ti0 == ti1) & (tj0 == tj1) & (ti0 == tj0));
    if (!(pure1 | pure2 | pure3)) return;

    const u16* q = pure2 ? qneg : qpos;
    const u16* k = pure3 ? kneg : kpos;

    int w = threadIdx.x >> 6, l = threadIdx.x & 63;
    size_t base = (size_t)bc * (SS * HH);
    int lin = (l & 15) * HH + ((l >> 4) * 8);
    int ar0 = m0 + w * 32;

    const u16* pq0 = q + base + (size_t)(ar0)      * HH + lin;
    const u16* pq1 = q + base + (size_t)(ar0 + 16) * HH + lin;
    const u16* pk0 = k + base + (size_t)(n0)       * HH + lin;
    const u16* pk1 = k + base + (size_t)(n0 + 16)  * HH + lin;
    const u16* pk2 = k + base + (size_t)(n0 + 32)  * HH + lin;
    const u16* pk3 = k + base + (size_t)(n0 + 48)  * HH + lin;

    f32x4 acc[2][4] = {};
    bf16x8 qA[2], kA[4], qB[2], kB[4];

#define LD(QQ, KK, kkq) do { \
    QQ[0] = loadfrag(pq0 + (kkq) * 32); QQ[1] = loadfrag(pq1 + (kkq) * 32); \
    KK[0] = loadfrag(pk0 + (kkq) * 32); KK[1] = loadfrag(pk1 + (kkq) * 32); \
    KK[2] = loadfrag(pk2 + (kkq) * 32); KK[3] = loadfrag(pk3 + (kkq) * 32); } while (0)
#define MM(QQ, KK) do { \
    _Pragma("unroll") \
    for (int mi = 0; mi < 2; ++mi) \
    _Pragma("unroll") \
    for (int ns = 0; ns < 4; ++ns) \
        acc[mi][ns] = __builtin_amdgcn_mfma_f32_16x16x32_bf16(QQ[mi], KK[ns], acc[mi][ns], 0, 0, 0); } while (0)

    LD(qA, kA, 0);
    LD(qB, kB, 1);
    MM(qA, kA); LD(qA, kA, 2);
    MM(qB, kB); LD(qB, kB, 3);
    MM(qA, kA); LD(qA, kA, 4);
    MM(qB, kB); LD(qB, kB, 5);
    MM(qA, kA); LD(qA, kA, 6);
    MM(qB, kB); LD(qB, kB, 7);
    MM(qA, kA);
    MM(qB, kB);
#undef LD
#undef MM

    float* ob = out + (size_t)bc * ((size_t)SS * SS);
#pragma unroll
    for (int mi = 0; mi < 2; ++mi)
#pragma unroll
        for (int ns = 0; ns < 4; ++ns)
#pragma unroll
            for (int r = 0; r < 4; ++r) {
                int m = ar0 + mi * 16 + (l >> 4) * 4 + r;
                int n = n0 + ns * 16 + (l & 15);
                ob[(size_t)m * SS + n] = acc[mi][ns][r];
            }
}

__global__ void __launch_bounds__(256) k2_mixed(
    const u16* __restrict__ qpos, const u16* __restrict__ qneg,
    const u16* __restrict__ kpos, const u16* __restrict__ kneg,
    const int* __restrict__ thread_id, float* __restrict__ out) {
    int wg = blockIdx.x;                     // 4096
    int swz = (wg & 7) * 512 + (wg >> 3);
    int bc = swz >> 7;
    int t = swz & 127;
    int m0 = (t >> 4) * 128, n0 = (t & 15) * 64;
    int b = bc >> 2;
    const int* tb = thread_id + b * SS;
    int ti0 = tb[m0], ti1 = tb[m0 + 127], tj0 = tb[n0], tj1 = tb[n0 + 63];
    bool pure2 = (ti0 > 0) & (ti1 < tj0);
    bool pure3 = (tj0 > 0) & (ti0 > tj1);
    bool pure1 = (ti1 == 0) | (tj1 == 0) | ((ti0 == ti1) & (tj0 == tj1) & (ti0 == tj0));
    if (pure1 | pure2 | pure3) return;

    // superset existence flags (safe over-approximations)
    bool need2 = (ti1 > 0) && (tj1 > ((ti0 > 0) ? ti0 : 1));
    bool need3 = (tj1 > 0) && (ti1 > ((tj0 > 0) ? tj0 : 1));
    bool need1 = (ti0 == 0) || (tj0 == 0) || ((ti0 <= tj1) && (tj0 <= ti1));

    int w = threadIdx.x >> 6, l = threadIdx.x & 63;
    size_t base = (size_t)bc * (SS * HH);
    int lin = (l & 15) * HH + ((l >> 4) * 8);
    int ar0 = m0 + w * 32;

    const u16* pqp[2]; const u16* pqn[2]; const u16* pkp[4]; const u16* pkn[4];
#pragma unroll
    for (int mi = 0; mi < 2; ++mi) {
        size_t o = base + (size_t)(ar0 + mi * 16) * HH + lin;
        pqp[mi] = qpos + o;
        pqn[mi] = qneg + o;
    }
#pragma unroll
    for (int ns = 0; ns < 4; ++ns) {
        size_t o = base + (size_t)(n0 + ns * 16) * HH + lin;
        pkp[ns] = kpos + o;
        pkn[ns] = kneg + o;
    }

    f32x4 a1[2][4] = {}, a2[2][4] = {}, a3[2][4] = {};
#pragma unroll
    for (int kk = 0; kk < 8; ++kk) {
        bf16x8 qpF[2], qnF[2], kpF[4], knF[4];
        if (need1 | need3) {
#pragma unroll
            for (int mi = 0; mi < 2; ++mi) qpF[mi] = loadfrag(pqp[mi] + kk * 32);
        }
        if (need2) {
#pragma unroll
            for (int mi = 0; mi < 2; ++mi) qnF[mi] = loadfrag(pqn[mi] + kk * 32);
        }
        if (need1 | need2) {
#pragma unroll
            for (int ns = 0; ns < 4; ++ns) kpF[ns] = loadfrag(pkp[ns] + kk * 32);
        }
        if (need3) {
#pragma unroll
            for (int ns = 0; ns < 4; ++ns) knF[ns] = loadfrag(pkn[ns] + kk * 32);
        }
        if (need1) {
#pragma unroll
            for (int mi = 0; mi < 2; ++mi)
#pragma unroll
                for (int ns = 0; ns < 4; ++ns)
                    a1[mi][ns] = __builtin_amdgcn_mfma_f32_16x16x32_bf16(qpF[mi], kpF[ns], a1[mi][ns], 0, 0, 0);
        }
        if (need2) {
#pragma unroll
            for (int mi = 0; mi < 2; ++mi)
#pragma unroll
                for (int ns = 0; ns < 4; ++ns)
                    a2[mi][ns] = __builtin_amdgcn_mfma_f32_16x16x32_bf16(qnF[mi], kpF[ns], a2[mi][ns], 0, 0, 0);
        }
        if (need3) {
#pragma unroll
            for (int mi = 0; mi < 2; ++mi)
#pragma unroll
                for (int ns = 0; ns < 4; ++ns)
                    a3[mi][ns] = __builtin_amdgcn_mfma_f32_16x16x32_bf16(qpF[mi], knF[ns], a3[mi][ns], 0, 0, 0);
        }
    }

    int tj[4], ti_[2][4];
#pragma unroll
    for (int ns = 0; ns < 4; ++ns) tj[ns] = tb[n0 + ns * 16 + (l & 15)];
#pragma unroll
    for (int mi = 0; mi < 2; ++mi)
#pragma unroll
        for (int r = 0; r < 4; ++r) ti_[mi][r] = tb[ar0 + mi * 16 + (l >> 4) * 4 + r];

    float* ob = out + (size_t)bc * ((size_t)SS * SS);
#pragma unroll
    for (int mi = 0; mi < 2; ++mi)
#pragma unroll
        for (int ns = 0; ns < 4; ++ns)
#pragma unroll
            for (int r = 0; r < 4; ++r) {
                int m = ar0 + mi * 16 + (l >> 4) * 4 + r;
                int n = n0 + ns * 16 + (l & 15);
                int ti = ti_[mi][r], tjj = tj[ns];
                float v = (ti > 0 && ti < tjj) ? a2[mi][ns][r]
                         : ((tjj > 0 && ti > tjj) ? a3[mi][ns][r] : a1[mi][ns][r]);
                ob[(size_t)m * SS + n] = v;
            }
}

extern "C" void kernel_launch(void* const* d_in, const int* in_sizes, int n_in,
                              void* d_out, int out_size, void* d_ws, size_t ws_size,
                              hipStream_t stream) {
    const float* x  = (const float*)d_in[0];
    const float* Wq = (const float*)d_in[1];
    const float* bq = (const float*)d_in[2];
    const float* Wk = (const float*)d_in[3];
    const float* bk = (const float*)d_in[4];
    const int* tok  = (const int*)d_in[5];
    const int* tid  = (const int*)d_in[6];
    float* out = (float*)d_out;

    char* ws = (char*)d_ws;
    const size_t MB = 1u << 20;
    u16* qpos = (u16*)(ws);
    u16* qneg = (u16*)(ws + 16 * MB);
    u16* kpos = (u16*)(ws + 32 * MB);
    u16* kneg = (u16*)(ws + 48 * MB);
    u16* xbf  = (u16*)(ws + 64 * MB);
    u16* Wt   = (u16*)(ws + 68 * MB);
    float2* trig = (float2*)(ws + 69 * MB);

    k0_castx<<<8192, 256, 0, stream>>>(x, xbf);
    k0_transw<<<2048, 256, 0, stream>>>(Wq, Wk, Wt);
    k0_trig<<<128, 256, 0, stream>>>(trig);
    k1_proj<<<4096, 256, 0, stream>>>(xbf, Wt, bq, bk, tok, trig, qpos, qneg, kpos, kneg);
    k2_pure<<<4096, 256, 0, stream>>>(qpos, qneg, kpos, kneg, tid, out);
    k2_mixed<<<4096, 256, 0, stream>>>(qpos, qneg, kpos, kneg, tid, out);
}

// Round 3
// 158.461 us; speedup vs baseline: 1.7856x; 1.7010x over previous
//
#include <hip/hip_runtime.h>

#define BB 8
#define SS 1024
#define HH 256
#define CC 4
#define NQ 1024  // H*C

typedef unsigned short u16;
typedef unsigned int u32;
typedef __attribute__((ext_vector_type(8))) __bf16 bf16x8;
typedef __attribute__((ext_vector_type(4))) float f32x4;
typedef __attribute__((ext_vector_type(4))) u32 u32x4;

__device__ __forceinline__ u16 f2bf(float f) {
    u32 u = __float_as_uint(f);
    u32 r = (u + 0x7FFFu + ((u >> 16) & 1u)) >> 16;
    return (u16)r;
}

// async global -> LDS, 16B per lane, wave-uniform LDS base + lane*16
__device__ __forceinline__ void gld16(const u16* g, u16* l) {
    __builtin_amdgcn_global_load_lds(
        (const __attribute__((address_space(1))) void*)g,
        (__attribute__((address_space(3))) void*)l, 16, 0, 0);
}

__device__ __forceinline__ bf16x8 ldsfrag(const u16* smem, int row, int c16) {
    // st-16x32-style XOR swizzle: 16B slot ^= (row & 7)
    const char* p = (const char*)smem + row * 128 + (((c16 ^ (row & 7)) & 7) << 4);
    return *(const bf16x8*)p;
}

// ---------- prep kernels ----------
__global__ void k0_castx(const float* __restrict__ x, u16* __restrict__ xbf) {
    int i = blockIdx.x * 256 + threadIdx.x;
    xbf[i] = f2bf(x[i]);
}

__global__ void k0_transw(const float* __restrict__ Wq, const float* __restrict__ Wk,
                          u16* __restrict__ Wt) {
    int i = blockIdx.x * 256 + threadIdx.x;  // 524,288
    int n = i >> 8, k = i & 255;
    float v = (n < NQ) ? Wq[k * NQ + n] : Wk[k * NQ + (n - NQ)];
    Wt[i] = f2bf(v);  // Wt[n][k]
}

__global__ void k0_trig(float2* __restrict__ trig) {
    int i = blockIdx.x * 256 + threadIdx.x;  // 32768
    int pos = i >> 7, f = i & 127;
    float freq = __expf(-(float)f * 0.07195578515529633f);
    float ang = (float)pos * freq;
    float s, c;
    sincosf(ang, &s, &c);
    trig[i] = make_float2(c, s);
}

// ---------- staging helpers (BK=64 chunk, row-major [rows][64] bf16 in LDS) ----------
// global row stride = 256 elems; source 16B-slot is XOR-preswizzled so that the
// linear LDS write lands data where ldsfrag()'s swizzled read expects it.
#define STAGE_A(dst, srcbase, row0cnt4, m_off, kc)                                  \
    _Pragma("unroll") for (int i_ = 0; i_ < (row0cnt4); ++i_) {                     \
        int r_ = w * 8 * (row0cnt4) + i_ * 8 + (l >> 3);                            \
        int c16_ = (l & 7) ^ (r_ & 7);                                              \
        gld16((srcbase) + (size_t)((m_off) + r_) * HH + (kc) * 64 + c16_ * 8,       \
              (dst) + (w * 8 * (row0cnt4) + i_ * 8) * 64);                          \
    }

// ---------- k1: projection GEMM + bias + RoPE epilogue ----------
// P(m,n) = sum_k xbf[m][k] * Wt[n][k]; m in [0,8192), n in [0,2048)
__global__ void __launch_bounds__(256) k1_proj(
    const u16* __restrict__ xbf, const u16* __restrict__ Wt,
    const float* __restrict__ bq, const float* __restrict__ bk,
    const int* __restrict__ tok, const float2* __restrict__ trig,
    u16* __restrict__ qpos, u16* __restrict__ qneg,
    u16* __restrict__ kpos, u16* __restrict__ kneg) {
    int wg = blockIdx.x;          // 2048 = 64 m-tiles x 32 n-tiles
    int m0 = (wg >> 5) * 128, n0 = (wg & 31) * 64;
    int w = threadIdx.x >> 6, l = threadIdx.x & 63;

    __shared__ u16 As[128 * 64];
    __shared__ u16 Bs[64 * 64];

    f32x4 acc[2][4] = {};
    for (int kc = 0; kc < 4; ++kc) {
        if (kc) __syncthreads();
        STAGE_A(As, xbf, 4, m0, kc)
        STAGE_A(Bs, Wt, 2, n0, kc)
        asm volatile("s_waitcnt vmcnt(0)" ::: "memory");
        __syncthreads();
#pragma unroll
        for (int ks = 0; ks < 2; ++ks) {
            int c16 = (l >> 4) + ks * 4;
            bf16x8 af[2], bfr[4];
#pragma unroll
            for (int mi = 0; mi < 2; ++mi) af[mi] = ldsfrag(As, w * 32 + mi * 16 + (l & 15), c16);
#pragma unroll
            for (int ns = 0; ns < 4; ++ns) bfr[ns] = ldsfrag(Bs, ns * 16 + (l & 15), c16);
#pragma unroll
            for (int mi = 0; mi < 2; ++mi)
#pragma unroll
                for (int ns = 0; ns < 4; ++ns)
                    acc[mi][ns] = __builtin_amdgcn_mfma_f32_16x16x32_bf16(af[mi], bfr[ns], acc[mi][ns], 0, 0, 0);
        }
    }

    // epilogue: bias + RoPE (pairs = adjacent cols = adjacent lanes)
#pragma unroll
    for (int mi = 0; mi < 2; ++mi)
#pragma unroll
        for (int ns = 0; ns < 4; ++ns) {
            int n = n0 + ns * 16 + (l & 15);
            bool isq = n < NQ;
            int nc = n & (NQ - 1);
            float bias = isq ? bq[nc] : bk[nc];
            int c = nc >> 8, h = nc & 255, fi = h >> 1;
#pragma unroll
            for (int r = 0; r < 4; ++r) {
                int m = m0 + w * 32 + mi * 16 + (l >> 4) * 4 + r;
                float val = acc[mi][ns][r] + bias;
                float other = __shfl_xor(val, 1);
                int pos = tok[m];
                float2 cs = trig[pos * 128 + fi];
                float rp, rn;
                if ((l & 1) == 0) {
                    rp = val * cs.x - other * cs.y;
                    rn = val * cs.x + other * cs.y;
                } else {
                    rp = other * cs.y + val * cs.x;
                    rn = -other * cs.y + val * cs.x;
                }
                int b = m >> 10, s = m & 1023;
                size_t oidx = ((size_t)((b << 2) | c) * SS + s) * HH + h;
                if (isq) {
                    qpos[oidx] = f2bf(rp);
                    qneg[oidx] = f2bf(rn);
                } else {
                    kpos[oidx] = f2bf(rp);
                    kneg[oidx] = f2bf(rn);
                }
            }
        }
}

// ---------- k2: pure tiles (one stream) ----------
__global__ void __launch_bounds__(256) k2_pure(
    const u16* __restrict__ qpos, const u16* __restrict__ qneg,
    const u16* __restrict__ kpos, const u16* __restrict__ kneg,
    const int* __restrict__ thread_id, float* __restrict__ out) {
    int wg = blockIdx.x;                     // 4096 (identity dispatch: XCD-balanced)
    int bc = wg >> 7;
    int t = wg & 127;
    int m0 = (t >> 4) * 128, n0 = (t & 15) * 64;
    const int* tb = thread_id + (bc >> 2) * SS;
    int ti0 = tb[m0], ti1 = tb[m0 + 127], tj0 = tb[n0], tj1 = tb[n0 + 63];
    bool pure2 = (ti0 > 0) & (ti1 < tj0);
    bool pure3 = (tj0 > 0) & (ti0 > tj1);
    bool pure1 = (ti1 == 0) | (tj1 == 0) | ((ti0 == ti1) & (tj0 == tj1) & (ti0 == tj0));
    if (!(pure1 | pure2 | pure3)) return;

    const u16* q = (pure2 ? qneg : qpos) + (size_t)bc * (SS * HH);
    const u16* k = (pure3 ? kneg : kpos) + (size_t)bc * (SS * HH);

    int w = threadIdx.x >> 6, l = threadIdx.x & 63;
    __shared__ u16 As[128 * 64];
    __shared__ u16 Bs[64 * 64];

    f32x4 acc[2][4] = {};
    for (int kc = 0; kc < 4; ++kc) {
        if (kc) __syncthreads();
        STAGE_A(As, q, 4, m0, kc)
        STAGE_A(Bs, k, 2, n0, kc)
        asm volatile("s_waitcnt vmcnt(0)" ::: "memory");
        __syncthreads();
#pragma unroll
        for (int ks = 0; ks < 2; ++ks) {
            int c16 = (l >> 4) + ks * 4;
            bf16x8 af[2], bfr[4];
#pragma unroll
            for (int mi = 0; mi < 2; ++mi) af[mi] = ldsfrag(As, w * 32 + mi * 16 + (l & 15), c16);
#pragma unroll
            for (int ns = 0; ns < 4; ++ns) bfr[ns] = ldsfrag(Bs, ns * 16 + (l & 15), c16);
#pragma unroll
            for (int mi = 0; mi < 2; ++mi)
#pragma unroll
                for (int ns = 0; ns < 4; ++ns)
                    acc[mi][ns] = __builtin_amdgcn_mfma_f32_16x16x32_bf16(af[mi], bfr[ns], acc[mi][ns], 0, 0, 0);
        }
    }

    float* ob = out + (size_t)bc * ((size_t)SS * SS);
#pragma unroll
    for (int mi = 0; mi < 2; ++mi)
#pragma unroll
        for (int ns = 0; ns < 4; ++ns)
#pragma unroll
            for (int r = 0; r < 4; ++r) {
                int m = m0 + w * 32 + mi * 16 + (l >> 4) * 4 + r;
                int n = n0 + ns * 16 + (l & 15);
                ob[(size_t)m * SS + n] = acc[mi][ns][r];
            }
}

// ---------- k2: mixed tiles (3 streams, branchless) ----------
__global__ void __launch_bounds__(256) k2_mixed(
    const u16* __restrict__ qpos, const u16* __restrict__ qneg,
    const u16* __restrict__ kpos, const u16* __restrict__ kneg,
    const int* __restrict__ thread_id, float* __restrict__ out) {
    int wg = blockIdx.x;                     // 4096
    int bc = wg >> 7;
    int t = wg & 127;
    int m0 = (t >> 4) * 128, n0 = (t & 15) * 64;
    const int* tb = thread_id + (bc >> 2) * SS;
    int ti0 = tb[m0], ti1 = tb[m0 + 127], tj0 = tb[n0], tj1 = tb[n0 + 63];
    bool pure2 = (ti0 > 0) & (ti1 < tj0);
    bool pure3 = (tj0 > 0) & (ti0 > tj1);
    bool pure1 = (ti1 == 0) | (tj1 == 0) | ((ti0 == ti1) & (tj0 == tj1) & (ti0 == tj0));
    if (pure1 | pure2 | pure3) return;

    size_t base = (size_t)bc * (SS * HH);
    const u16* qp = qpos + base;
    const u16* qn = qneg + base;
    const u16* kp = kpos + base;
    const u16* kn = kneg + base;

    int w = threadIdx.x >> 6, l = threadIdx.x & 63;
    __shared__ u16 Aq[2][128 * 64];   // qpos, qneg
    __shared__ u16 Bk[2][64 * 64];    // kpos, kneg

    f32x4 a1[2][4] = {}, a2[2][4] = {}, a3[2][4] = {};
    for (int kc = 0; kc < 4; ++kc) {
        if (kc) __syncthreads();
        STAGE_A(Aq[0], qp, 4, m0, kc)
        STAGE_A(Aq[1], qn, 4, m0, kc)
        STAGE_A(Bk[0], kp, 2, n0, kc)
        STAGE_A(Bk[1], kn, 2, n0, kc)
        asm volatile("s_waitcnt vmcnt(0)" ::: "memory");
        __syncthreads();
#pragma unroll
        for (int ks = 0; ks < 2; ++ks) {
            int c16 = (l >> 4) + ks * 4;
            bf16x8 qpF[2], qnF[2], kpF[4], knF[4];
#pragma unroll
            for (int mi = 0; mi < 2; ++mi) {
                int rr = w * 32 + mi * 16 + (l & 15);
                qpF[mi] = ldsfrag(Aq[0], rr, c16);
                qnF[mi] = ldsfrag(Aq[1], rr, c16);
            }
#pragma unroll
            for (int ns = 0; ns < 4; ++ns) {
                int rn = ns * 16 + (l & 15);
                kpF[ns] = ldsfrag(Bk[0], rn, c16);
                knF[ns] = ldsfrag(Bk[1], rn, c16);
            }
#pragma unroll
            for (int mi = 0; mi < 2; ++mi)
#pragma unroll
                for (int ns = 0; ns < 4; ++ns) {
                    a1[mi][ns] = __builtin_amdgcn_mfma_f32_16x16x32_bf16(qpF[mi], kpF[ns], a1[mi][ns], 0, 0, 0);
                    a2[mi][ns] = __builtin_amdgcn_mfma_f32_16x16x32_bf16(qnF[mi], kpF[ns], a2[mi][ns], 0, 0, 0);
                    a3[mi][ns] = __builtin_amdgcn_mfma_f32_16x16x32_bf16(qpF[mi], knF[ns], a3[mi][ns], 0, 0, 0);
                }
        }
    }

    int tj[4], ti_[2][4];
#pragma unroll
    for (int ns = 0; ns < 4; ++ns) tj[ns] = tb[n0 + ns * 16 + (l & 15)];
#pragma unroll
    for (int mi = 0; mi < 2; ++mi)
#pragma unroll
        for (int r = 0; r < 4; ++r) ti_[mi][r] = tb[m0 + w * 32 + mi * 16 + (l >> 4) * 4 + r];

    float* ob = out + (size_t)bc * ((size_t)SS * SS);
#pragma unroll
    for (int mi = 0; mi < 2; ++mi)
#pragma unroll
        for (int ns = 0; ns < 4; ++ns)
#pragma unroll
            for (int r = 0; r < 4; ++r) {
                int m = m0 + w * 32 + mi * 16 + (l >> 4) * 4 + r;
                int n = n0 + ns * 16 + (l & 15);
                int ti = ti_[mi][r], tjj = tj[ns];
                float v = (ti > 0 && ti < tjj) ? a2[mi][ns][r]
                         : ((tjj > 0 && ti > tjj) ? a3[mi][ns][r] : a1[mi][ns][r]);
                ob[(size_t)m * SS + n] = v;
            }
}

extern "C" void kernel_launch(void* const* d_in, const int* in_sizes, int n_in,
                              void* d_out, int out_size, void* d_ws, size_t ws_size,
                              hipStream_t stream) {
    const float* x  = (const float*)d_in[0];
    const float* Wq = (const float*)d_in[1];
    const float* bq = (const float*)d_in[2];
    const float* Wk = (const float*)d_in[3];
    const float* bk = (const float*)d_in[4];
    const int* tok  = (const int*)d_in[5];
    const int* tid  = (const int*)d_in[6];
    float* out = (float*)d_out;

    char* ws = (char*)d_ws;
    const size_t MB = 1u << 20;
    u16* qpos = (u16*)(ws);
    u16* qneg = (u16*)(ws + 16 * MB);
    u16* kpos = (u16*)(ws + 32 * MB);
    u16* kneg = (u16*)(ws + 48 * MB);
    u16* xbf  = (u16*)(ws + 64 * MB);
    u16* Wt   = (u16*)(ws + 68 * MB);
    float2* trig = (float2*)(ws + 69 * MB);

    k0_castx<<<8192, 256, 0, stream>>>(x, xbf);
    k0_transw<<<2048, 256, 0, stream>>>(Wq, Wk, Wt);
    k0_trig<<<128, 256, 0, stream>>>(trig);
    k1_proj<<<2048, 256, 0, stream>>>(xbf, Wt, bq, bk, tok, trig, qpos, qneg, kpos, kneg);
    k2_pure<<<4096, 256, 0, stream>>>(qpos, qneg, kpos, kneg, tid, out);
    k2_mixed<<<4096, 256, 0, stream>>>(qpos, qneg, kpos, kneg, tid, out);
}

// Round 4
// 135.849 us; speedup vs baseline: 2.0828x; 1.1665x over previous
//
#include <hip/hip_runtime.h>

#define BB 8
#define SS 1024
#define HH 256
#define CC 4
#define NQ 1024  // H*C

typedef unsigned short u16;
typedef unsigned int u32;
typedef __attribute__((ext_vector_type(8))) __bf16 bf16x8;
typedef __attribute__((ext_vector_type(4))) float f32x4;
typedef __attribute__((ext_vector_type(4))) u32 u32x4;
typedef __attribute__((ext_vector_type(4))) u16 u16x4;

__device__ __forceinline__ u16 f2bf(float f) {
    u32 u = __float_as_uint(f);
    u32 r = (u + 0x7FFFu + ((u >> 16) & 1u)) >> 16;
    return (u16)r;
}

// async global -> LDS, 16B per lane, wave-uniform LDS base + lane*16
__device__ __forceinline__ void gld16(const u16* g, u16* l) {
    __builtin_amdgcn_global_load_lds(
        (const __attribute__((address_space(1))) void*)g,
        (__attribute__((address_space(3))) void*)l, 16, 0, 0);
}

__device__ __forceinline__ bf16x8 ldsfrag(const u16* smem, int row, int c16) {
    // st-16x32-style XOR swizzle: 16B slot ^= (row & 7)
    const char* p = (const char*)smem + row * 128 + (((c16 ^ (row & 7)) & 7) << 4);
    return *(const bf16x8*)p;
}

// ---------- prep kernels ----------
__global__ void k0_castx(const float4* __restrict__ x, u16x4* __restrict__ xbf) {
    int i = blockIdx.x * 256 + threadIdx.x;  // 524,288
    float4 v = x[i];
    u16x4 o = {f2bf(v.x), f2bf(v.y), f2bf(v.z), f2bf(v.w)};
    xbf[i] = o;
}

// LDS-tiled transpose: Wt[n][k] from Wq/Wk[k][n], coalesced both sides
__global__ void k0_transw(const float* __restrict__ Wq, const float* __restrict__ Wk,
                          u16* __restrict__ Wt) {
    __shared__ u16 tl[64][65];
    int nb = blockIdx.x * 64, kb = blockIdx.y * 64;
    int c = threadIdx.x & 63;
#pragma unroll
    for (int r = threadIdx.x >> 6; r < 64; r += 4) {
        int k = kb + r, n = nb + c;
        float v = (n < NQ) ? Wq[k * NQ + n] : Wk[k * NQ + (n - NQ)];
        tl[c][r] = f2bf(v);   // tl[n][k]
    }
    __syncthreads();
#pragma unroll
    for (int r = threadIdx.x >> 6; r < 64; r += 4) {
        Wt[(size_t)(nb + r) * HH + kb + c] = tl[r][c];
    }
}

__global__ void k0_trig(float2* __restrict__ trig) {
    int i = blockIdx.x * 256 + threadIdx.x;  // 32768
    int pos = i >> 7, f = i & 127;
    float freq = __expf(-(float)f * 0.07195578515529633f);
    float ang = (float)pos * freq;
    float s, c;
    sincosf(ang, &s, &c);
    trig[i] = make_float2(c, s);
}

// ---------- staging (BK=64 chunk, [rows][64] bf16 in LDS, source-preswizzled) ----------
#define STAGE_A(dst, srcbase, row0cnt4, m_off, kc)                                  \
    _Pragma("unroll") for (int i_ = 0; i_ < (row0cnt4); ++i_) {                     \
        int r_ = w * 8 * (row0cnt4) + i_ * 8 + (l >> 3);                            \
        int c16_ = (l & 7) ^ (r_ & 7);                                              \
        gld16((srcbase) + (size_t)((m_off) + r_) * HH + (kc) * 64 + c16_ * 8,       \
              (dst) + (w * 8 * (row0cnt4) + i_ * 8) * 64);                          \
    }

// ---------- k1: projection GEMM + bias + RoPE, double-buffered ----------
__global__ void __launch_bounds__(256) k1_proj(
    const u16* __restrict__ xbf, const u16* __restrict__ Wt,
    const float* __restrict__ bq, const float* __restrict__ bk,
    const int* __restrict__ tok, const float2* __restrict__ trig,
    u16* __restrict__ qpos, u16* __restrict__ qneg,
    u16* __restrict__ kpos, u16* __restrict__ kneg) {
    int wg = blockIdx.x;          // 2048 = 64 m-tiles x 32 n-tiles
    int m0 = (wg >> 5) * 128, n0 = (wg & 31) * 64;
    int w = threadIdx.x >> 6, l = threadIdx.x & 63;

    __shared__ u16 sm[24576];     // 48 KB: 2 x (A 8192 + B 4096)
    u16* Ab[2] = {sm, sm + 12288};
    u16* Bb[2] = {sm + 8192, sm + 20480};

    f32x4 acc[2][4] = {};
    STAGE_A(Ab[0], xbf, 4, m0, 0)
    STAGE_A(Bb[0], Wt, 2, n0, 0)
    asm volatile("s_waitcnt vmcnt(0)" ::: "memory");
    __builtin_amdgcn_s_barrier();
#pragma unroll
    for (int kc = 0; kc < 4; ++kc) {
        u16* As = Ab[kc & 1];
        u16* Bs = Bb[kc & 1];
        if (kc < 3) {
            STAGE_A(Ab[(kc + 1) & 1], xbf, 4, m0, kc + 1)
            STAGE_A(Bb[(kc + 1) & 1], Wt, 2, n0, kc + 1)
        }
#pragma unroll
        for (int ks = 0; ks < 2; ++ks) {
            int c16 = (l >> 4) + ks * 4;
            bf16x8 af[2], bfr[4];
#pragma unroll
            for (int mi = 0; mi < 2; ++mi) af[mi] = ldsfrag(As, w * 32 + mi * 16 + (l & 15), c16);
#pragma unroll
            for (int ns = 0; ns < 4; ++ns) bfr[ns] = ldsfrag(Bs, ns * 16 + (l & 15), c16);
#pragma unroll
            for (int mi = 0; mi < 2; ++mi)
#pragma unroll
                for (int ns = 0; ns < 4; ++ns)
                    acc[mi][ns] = __builtin_amdgcn_mfma_f32_16x16x32_bf16(af[mi], bfr[ns], acc[mi][ns], 0, 0, 0);
        }
        if (kc < 3) {
            asm volatile("s_waitcnt vmcnt(0) lgkmcnt(0)" ::: "memory");
            __builtin_amdgcn_s_barrier();
        }
    }

#pragma unroll
    for (int mi = 0; mi < 2; ++mi)
#pragma unroll
        for (int ns = 0; ns < 4; ++ns) {
            int n = n0 + ns * 16 + (l & 15);
            bool isq = n < NQ;
            int nc = n & (NQ - 1);
            float bias = isq ? bq[nc] : bk[nc];
            int c = nc >> 8, h = nc & 255, fi = h >> 1;
#pragma unroll
            for (int r = 0; r < 4; ++r) {
                int m = m0 + w * 32 + mi * 16 + (l >> 4) * 4 + r;
                float val = acc[mi][ns][r] + bias;
                float other = __shfl_xor(val, 1);
                int pos = tok[m];
                float2 cs = trig[pos * 128 + fi];
                float rp, rn;
                if ((l & 1) == 0) {
                    rp = val * cs.x - other * cs.y;
                    rn = val * cs.x + other * cs.y;
                } else {
                    rp = other * cs.y + val * cs.x;
                    rn = -other * cs.y + val * cs.x;
                }
                int b = m >> 10, s = m & 1023;
                size_t oidx = ((size_t)((b << 2) | c) * SS + s) * HH + h;
                if (isq) {
                    qpos[oidx] = f2bf(rp);
                    qneg[oidx] = f2bf(rn);
                } else {
                    kpos[oidx] = f2bf(rp);
                    kneg[oidx] = f2bf(rn);
                }
            }
        }
}

// ---------- k2: merged pure+mixed ----------
__global__ void __launch_bounds__(256) k2_gemm(
    const u16* __restrict__ qpos, const u16* __restrict__ qneg,
    const u16* __restrict__ kpos, const u16* __restrict__ kneg,
    const int* __restrict__ thread_id, float* __restrict__ out) {
    int wg = blockIdx.x;                     // 4096 (identity: XCD-balanced)
    int bc = wg >> 7;
    int t = wg & 127;
    int m0 = (t >> 4) * 128, n0 = (t & 15) * 64;
    const int* tb = thread_id + (bc >> 2) * SS;
    int w = threadIdx.x >> 6, l = threadIdx.x & 63;
    int ti0 = tb[m0], ti1 = tb[m0 + 127], tj0 = tb[n0], tj1 = tb[n0 + 63];
    bool pure2 = (ti0 > 0) & (ti1 < tj0);
    bool pure3 = (tj0 > 0) & (ti0 > tj1);
    bool pure1 = (ti1 == 0) | (tj1 == 0) | ((ti0 == ti1) & (tj0 == tj1) & (ti0 == tj0));
    size_t base = (size_t)bc * (SS * HH);
    float* ob = out + (size_t)bc * ((size_t)SS * SS);
    int ar0 = m0 + w * 32;

    __shared__ u16 sm[24576];     // 48 KB union

    if (pure1 | pure2 | pure3) {
        // ---- pure path: one stream, double-buffered ----
        const u16* q = (pure2 ? qneg : qpos) + base;
        const u16* k = (pure3 ? kneg : kpos) + base;
        u16* Ab[2] = {sm, sm + 12288};
        u16* Bb[2] = {sm + 8192, sm + 20480};

        f32x4 acc[2][4] = {};
        STAGE_A(Ab[0], q, 4, m0, 0)
        STAGE_A(Bb[0], k, 2, n0, 0)
        asm volatile("s_waitcnt vmcnt(0)" ::: "memory");
        __builtin_amdgcn_s_barrier();
#pragma unroll
        for (int kc = 0; kc < 4; ++kc) {
            u16* As = Ab[kc & 1];
            u16* Bs = Bb[kc & 1];
            if (kc < 3) {
                STAGE_A(Ab[(kc + 1) & 1], q, 4, m0, kc + 1)
                STAGE_A(Bb[(kc + 1) & 1], k, 2, n0, kc + 1)
            }
#pragma unroll
            for (int ks = 0; ks < 2; ++ks) {
                int c16 = (l >> 4) + ks * 4;
                bf16x8 af[2], bfr[4];
#pragma unroll
                for (int mi = 0; mi < 2; ++mi) af[mi] = ldsfrag(As, w * 32 + mi * 16 + (l & 15), c16);
#pragma unroll
                for (int ns = 0; ns < 4; ++ns) bfr[ns] = ldsfrag(Bs, ns * 16 + (l & 15), c16);
#pragma unroll
                for (int mi = 0; mi < 2; ++mi)
#pragma unroll
                    for (int ns = 0; ns < 4; ++ns)
                        acc[mi][ns] = __builtin_amdgcn_mfma_f32_16x16x32_bf16(af[mi], bfr[ns], acc[mi][ns], 0, 0, 0);
            }
            if (kc < 3) {
                asm volatile("s_waitcnt vmcnt(0) lgkmcnt(0)" ::: "memory");
                __builtin_amdgcn_s_barrier();
            }
        }

#pragma unroll
        for (int mi = 0; mi < 2; ++mi)
#pragma unroll
            for (int ns = 0; ns < 4; ++ns)
#pragma unroll
                for (int r = 0; r < 4; ++r) {
                    int m = ar0 + mi * 16 + (l >> 4) * 4 + r;
                    int n = n0 + ns * 16 + (l & 15);
                    ob[(size_t)m * SS + n] = acc[mi][ns][r];
                }
    } else {
        // ---- mixed path: up-to-3 streams with per-fragment skip ----
        const u16* qp = qpos + base;
        const u16* qn = qneg + base;
        const u16* kp = kpos + base;
        const u16* kn = kneg + base;
        u16* smqp = sm;
        u16* smqn = sm + 8192;
        u16* smkp = sm + 16384;
        u16* smkn = sm + 20480;

        // block-level staging flags
        int bamin = ti0 > 1 ? ti0 : 1;
        int bcmin = tj0 > 1 ? tj0 : 1;
        bool B2 = (ti1 > 0) && (tj1 > bamin);
        bool B3 = (tj1 > 0) && (ti1 > bcmin);

        // per-fragment need masks (bit = mi*4+ns), wave-uniform -> SGPR
        int fa[2], fb[2], fc[4], fd[4];
#pragma unroll
        for (int mi = 0; mi < 2; ++mi) {
            fa[mi] = tb[ar0 + mi * 16];
            fb[mi] = tb[ar0 + mi * 16 + 15];
        }
#pragma unroll
        for (int ns = 0; ns < 4; ++ns) {
            fc[ns] = tb[n0 + ns * 16];
            fd[ns] = tb[n0 + ns * 16 + 15];
        }
        u32 msk1 = 0, msk2 = 0, msk3 = 0;
#pragma unroll
        for (int mi = 0; mi < 2; ++mi)
#pragma unroll
            for (int ns = 0; ns < 4; ++ns) {
                u32 bit = 1u << (mi * 4 + ns);
                if ((fa[mi] == 0) | (fc[ns] == 0) | ((fa[mi] <= fd[ns]) & (fc[ns] <= fb[mi]))) msk1 |= bit;
                int amin = fa[mi] > 1 ? fa[mi] : 1;
                if ((fb[mi] > 0) & (fd[ns] > amin)) msk2 |= bit;
                int cmin = fc[ns] > 1 ? fc[ns] : 1;
                if ((fd[ns] > 0) & (fb[mi] > cmin)) msk3 |= bit;
            }
        msk1 = __builtin_amdgcn_readfirstlane(msk1);
        msk2 = __builtin_amdgcn_readfirstlane(msk2);
        msk3 = __builtin_amdgcn_readfirstlane(msk3);

        f32x4 a1[2][4] = {}, a2[2][4] = {}, a3[2][4] = {};
        for (int kc = 0; kc < 4; ++kc) {
            if (kc) __builtin_amdgcn_s_barrier();
            STAGE_A(smqp, qp, 4, m0, kc)
            if (B2) STAGE_A(smqn, qn, 4, m0, kc)
            STAGE_A(smkp, kp, 2, n0, kc)
            if (B3) STAGE_A(smkn, kn, 2, n0, kc)
            asm volatile("s_waitcnt vmcnt(0)" ::: "memory");
            __builtin_amdgcn_s_barrier();
#pragma unroll
            for (int ks = 0; ks < 2; ++ks) {
                int c16 = (l >> 4) + ks * 4;
                bf16x8 qpF[2], qnF[2], kpF[4], knF[4];
#pragma unroll
                for (int mi = 0; mi < 2; ++mi) {
                    int rr = w * 32 + mi * 16 + (l & 15);
                    qpF[mi] = ldsfrag(smqp, rr, c16);
                    if (msk2) qnF[mi] = ldsfrag(smqn, rr, c16);
                }
#pragma unroll
                for (int ns = 0; ns < 4; ++ns) {
                    int rn = ns * 16 + (l & 15);
                    kpF[ns] = ldsfrag(smkp, rn, c16);
                    if (msk3) knF[ns] = ldsfrag(smkn, rn, c16);
                }
#pragma unroll
                for (int mi = 0; mi < 2; ++mi)
#pragma unroll
                    for (int ns = 0; ns < 4; ++ns) {
                        u32 bit = 1u << (mi * 4 + ns);
                        if (msk1 & bit)
                            a1[mi][ns] = __builtin_amdgcn_mfma_f32_16x16x32_bf16(qpF[mi], kpF[ns], a1[mi][ns], 0, 0, 0);
                        if (msk2 & bit)
                            a2[mi][ns] = __builtin_amdgcn_mfma_f32_16x16x32_bf16(qnF[mi], kpF[ns], a2[mi][ns], 0, 0, 0);
                        if (msk3 & bit)
                            a3[mi][ns] = __builtin_amdgcn_mfma_f32_16x16x32_bf16(qpF[mi], knF[ns], a3[mi][ns], 0, 0, 0);
                    }
            }
        }

        int tj[4], ti_[2][4];
#pragma unroll
        for (int ns = 0; ns < 4; ++ns) tj[ns] = tb[n0 + ns * 16 + (l & 15)];
#pragma unroll
        for (int mi = 0; mi < 2; ++mi)
#pragma unroll
            for (int r = 0; r < 4; ++r) ti_[mi][r] = tb[ar0 + mi * 16 + (l >> 4) * 4 + r];

#pragma unroll
        for (int mi = 0; mi < 2; ++mi)
#pragma unroll
            for (int ns = 0; ns < 4; ++ns)
#pragma unroll
                for (int r = 0; r < 4; ++r) {
                    int m = ar0 + mi * 16 + (l >> 4) * 4 + r;
                    int n = n0 + ns * 16 + (l & 15);
                    int ti = ti_[mi][r], tjj = tj[ns];
                    float v = (ti > 0 && ti < tjj) ? a2[mi][ns][r]
                             : ((tjj > 0 && ti > tjj) ? a3[mi][ns][r] : a1[mi][ns][r]);
                    ob[(size_t)m * SS + n] = v;
                }
    }
}

extern "C" void kernel_launch(void* const* d_in, const int* in_sizes, int n_in,
                              void* d_out, int out_size, void* d_ws, size_t ws_size,
                              hipStream_t stream) {
    const float* x  = (const float*)d_in[0];
    const float* Wq = (const float*)d_in[1];
    const float* bq = (const float*)d_in[2];
    const float* Wk = (const float*)d_in[3];
    const float* bk = (const float*)d_in[4];
    const int* tok  = (const int*)d_in[5];
    const int* tid  = (const int*)d_in[6];
    float* out = (float*)d_out;

    char* ws = (char*)d_ws;
    const size_t MB = 1u << 20;
    u16* qpos = (u16*)(ws);
    u16* qneg = (u16*)(ws + 16 * MB);
    u16* kpos = (u16*)(ws + 32 * MB);
    u16* kneg = (u16*)(ws + 48 * MB);
    u16* xbf  = (u16*)(ws + 64 * MB);
    u16* Wt   = (u16*)(ws + 68 * MB);
    float2* trig = (float2*)(ws + 69 * MB);

    k0_castx<<<2048, 256, 0, stream>>>((const float4*)x, (u16x4*)xbf);
    dim3 tg(32, 4);
    k0_transw<<<tg, 256, 0, stream>>>(Wq, Wk, Wt);
    k0_trig<<<128, 256, 0, stream>>>(trig);
    k1_proj<<<2048, 256, 0, stream>>>(xbf, Wt, bq, bk, tok, trig, qpos, qneg, kpos, kneg);
    k2_gemm<<<4096, 256, 0, stream>>>(qpos, qneg, kpos, kneg, tid, out);
}

// Round 5
// 123.499 us; speedup vs baseline: 2.2911x; 1.1000x over previous
//
#include <hip/hip_runtime.h>

#define BB 8
#define SS 1024
#define HH 256
#define CC 4
#define NQ 1024  // H*C

typedef unsigned short u16;
typedef unsigned int u32;
typedef __attribute__((ext_vector_type(8))) __bf16 bf16x8;
typedef __attribute__((ext_vector_type(4))) float f32x4;
typedef __attribute__((ext_vector_type(4))) u32 u32x4;
typedef __attribute__((ext_vector_type(4))) u16 u16x4;

__device__ __forceinline__ u16 f2bf(float f) {
    u32 u = __float_as_uint(f);
    u32 r = (u + 0x7FFFu + ((u >> 16) & 1u)) >> 16;
    return (u16)r;
}

// async global -> LDS, 16B/lane, wave-uniform LDS base + lane*16
__device__ __forceinline__ void gld16(const u16* g, u16* l) {
    __builtin_amdgcn_global_load_lds(
        (const __attribute__((address_space(1))) void*)g,
        (__attribute__((address_space(3))) void*)l, 16, 0, 0);
}

__device__ __forceinline__ bf16x8 ldsfrag(const u16* smem, int row, int c16) {
    // 16B slot ^= (row & 7) swizzle
    const char* p = (const char*)smem + row * 128 + (((c16 ^ (row & 7)) & 7) << 4);
    return *(const bf16x8*)p;
}

// ---------- prep ----------
__global__ void k0_castx(const float4* __restrict__ x, u16x4* __restrict__ xbf) {
    int i = blockIdx.x * 256 + threadIdx.x;  // 524,288
    float4 v = x[i];
    u16x4 o = {f2bf(v.x), f2bf(v.y), f2bf(v.z), f2bf(v.w)};
    xbf[i] = o;
}

__global__ void k0_transw(const float* __restrict__ Wq, const float* __restrict__ Wk,
                          u16* __restrict__ Wt) {
    __shared__ u16 tl[64][65];
    int nb = blockIdx.x * 64, kb = blockIdx.y * 64;
    int c = threadIdx.x & 63;
#pragma unroll
    for (int r = threadIdx.x >> 6; r < 64; r += 4) {
        int k = kb + r, n = nb + c;
        float v = (n < NQ) ? Wq[k * NQ + n] : Wk[k * NQ + (n - NQ)];
        tl[c][r] = f2bf(v);
    }
    __syncthreads();
#pragma unroll
    for (int r = threadIdx.x >> 6; r < 64; r += 4) {
        Wt[(size_t)(nb + r) * HH + kb + c] = tl[r][c];
    }
}

__global__ void k0_trig(float2* __restrict__ trig) {
    int i = blockIdx.x * 256 + threadIdx.x;  // 32768
    int pos = i >> 7, f = i & 127;
    float freq = __expf(-(float)f * 0.07195578515529633f);
    float ang = (float)pos * freq;
    float s, c;
    sincosf(ang, &s, &c);
    trig[i] = make_float2(c, s);
}

// ---------- staging: [128][64] bf16 chunk, 512 threads, source-preswizzled ----------
#define STAGE2(dst, srcbase, roff, kc)                                          \
    _Pragma("unroll") for (int i_ = 0; i_ < 2; ++i_) {                          \
        int r_ = ww * 16 + i_ * 8 + (l >> 3);                                   \
        int c16_ = (l & 7) ^ (r_ & 7);                                          \
        gld16((srcbase) + (size_t)((roff) + r_) * HH + (kc) * 64 + c16_ * 8,    \
              (dst) + (ww * 16 + i_ * 8) * 64);                                 \
    }

// ---------- k1: projection + bias + RoPE (128x128, 512 thr, dbuf) ----------
__global__ void __launch_bounds__(512, 2) k1_proj(
    const u16* __restrict__ xbf, const u16* __restrict__ Wt,
    const float* __restrict__ bq, const float* __restrict__ bk,
    const int* __restrict__ tok, const float2* __restrict__ trig,
    u16* __restrict__ qpos, u16* __restrict__ qneg,
    u16* __restrict__ kpos, u16* __restrict__ kneg) {
    int h = blockIdx.x;                       // 1024 = 64 m x 16 n
    int logical = (h & 7) * 128 + (h >> 3);   // XCD-chunked
    int m0 = (logical >> 4) * 128, n0 = (logical & 15) * 128;
    int ww = threadIdx.x >> 6, l = threadIdx.x & 63;
    int wr = ww >> 1, wc = ww & 1;

    __shared__ u16 sm[32768];  // 64 KB
    u16* Ab[2] = {sm, sm + 16384};
    u16* Bb[2] = {sm + 8192, sm + 24576};

    f32x4 acc[2][4] = {};
    STAGE2(Ab[0], xbf, m0, 0)
    STAGE2(Bb[0], Wt, n0, 0)
    asm volatile("s_waitcnt vmcnt(0)" ::: "memory");
    __builtin_amdgcn_s_barrier();
#pragma unroll
    for (int kc = 0; kc < 4; ++kc) {
        u16* As = Ab[kc & 1];
        u16* Bs = Bb[kc & 1];
        if (kc < 3) {
            STAGE2(Ab[(kc + 1) & 1], xbf, m0, kc + 1)
            STAGE2(Bb[(kc + 1) & 1], Wt, n0, kc + 1)
        }
#pragma unroll
        for (int ks = 0; ks < 2; ++ks) {
            int c16 = (l >> 4) + ks * 4;
            bf16x8 af[2], bfr[4];
#pragma unroll
            for (int mi = 0; mi < 2; ++mi) af[mi] = ldsfrag(As, wr * 32 + mi * 16 + (l & 15), c16);
#pragma unroll
            for (int ns = 0; ns < 4; ++ns) bfr[ns] = ldsfrag(Bs, wc * 64 + ns * 16 + (l & 15), c16);
#pragma unroll
            for (int mi = 0; mi < 2; ++mi)
#pragma unroll
                for (int ns = 0; ns < 4; ++ns)
                    acc[mi][ns] = __builtin_amdgcn_mfma_f32_16x16x32_bf16(af[mi], bfr[ns], acc[mi][ns], 0, 0, 0);
        }
        if (kc < 3) {
            asm volatile("s_waitcnt vmcnt(0) lgkmcnt(0)" ::: "memory");
            __builtin_amdgcn_s_barrier();
        }
    }

#pragma unroll
    for (int mi = 0; mi < 2; ++mi)
#pragma unroll
        for (int ns = 0; ns < 4; ++ns) {
            int n = n0 + wc * 64 + ns * 16 + (l & 15);
            bool isq = n < NQ;
            int nc = n & (NQ - 1);
            float bias = isq ? bq[nc] : bk[nc];
            int c = nc >> 8, hh = nc & 255, fi = hh >> 1;
#pragma unroll
            for (int r = 0; r < 4; ++r) {
                int m = m0 + wr * 32 + mi * 16 + (l >> 4) * 4 + r;
                float val = acc[mi][ns][r] + bias;
                float other = __shfl_xor(val, 1);
                int pos = tok[m];
                float2 cs = trig[pos * 128 + fi];
                float rp, rn;
                if ((l & 1) == 0) {
                    rp = val * cs.x - other * cs.y;
                    rn = val * cs.x + other * cs.y;
                } else {
                    rp = other * cs.y + val * cs.x;
                    rn = -other * cs.y + val * cs.x;
                }
                int b = m >> 10, s = m & 1023;
                size_t oidx = ((size_t)((b << 2) | c) * SS + s) * HH + hh;
                if (isq) {
                    qpos[oidx] = f2bf(rp);
                    qneg[oidx] = f2bf(rn);
                } else {
                    kpos[oidx] = f2bf(rp);
                    kneg[oidx] = f2bf(rn);
                }
            }
        }
}

// ---------- k2: merged pure+mixed, 128x128, 512 thr, XCD-chunked ----------
__global__ void __launch_bounds__(512, 2) k2_gemm(
    const u16* __restrict__ qpos, const u16* __restrict__ qneg,
    const u16* __restrict__ kpos, const u16* __restrict__ kneg,
    const int* __restrict__ thread_id, float* __restrict__ out) {
    int h = blockIdx.x;                        // 2048
    int logical = (h & 7) * 256 + (h >> 3);    // XCD x gets logicals x*256.. in order
    int bc = logical >> 6;                     // 4 consecutive bc per XCD
    int t = logical & 63;
    int m0 = (t >> 3) * 128, n0 = (t & 7) * 128;  // n-inner: A-tile shared
    const int* tb = thread_id + (bc >> 2) * SS;
    int ww = threadIdx.x >> 6, l = threadIdx.x & 63;
    int wr = ww >> 1, wc = ww & 1;
    int ti0 = tb[m0], ti1 = tb[m0 + 127], tj0 = tb[n0], tj1 = tb[n0 + 127];
    bool pure2 = (ti0 > 0) & (ti1 < tj0);
    bool pure3 = (tj0 > 0) & (ti0 > tj1);
    bool pure1 = (ti1 == 0) | (tj1 == 0) | ((ti0 == ti1) & (tj0 == tj1) & (ti0 == tj0));
    size_t base = (size_t)bc * (SS * HH);
    float* ob = out + (size_t)bc * ((size_t)SS * SS);
    int ar0 = m0 + wr * 32;
    int nb0 = n0 + wc * 64;

    __shared__ u16 sm[32768];  // 64 KB union

    if (pure1 | pure2 | pure3) {
        const u16* q = (pure2 ? qneg : qpos) + base;
        const u16* k = (pure3 ? kneg : kpos) + base;
        u16* Ab[2] = {sm, sm + 16384};
        u16* Bb[2] = {sm + 8192, sm + 24576};

        f32x4 acc[2][4] = {};
        STAGE2(Ab[0], q, m0, 0)
        STAGE2(Bb[0], k, n0, 0)
        asm volatile("s_waitcnt vmcnt(0)" ::: "memory");
        __builtin_amdgcn_s_barrier();
#pragma unroll
        for (int kc = 0; kc < 4; ++kc) {
            u16* As = Ab[kc & 1];
            u16* Bs = Bb[kc & 1];
            if (kc < 3) {
                STAGE2(Ab[(kc + 1) & 1], q, m0, kc + 1)
                STAGE2(Bb[(kc + 1) & 1], k, n0, kc + 1)
            }
#pragma unroll
            for (int ks = 0; ks < 2; ++ks) {
                int c16 = (l >> 4) + ks * 4;
                bf16x8 af[2], bfr[4];
#pragma unroll
                for (int mi = 0; mi < 2; ++mi) af[mi] = ldsfrag(As, wr * 32 + mi * 16 + (l & 15), c16);
#pragma unroll
                for (int ns = 0; ns < 4; ++ns) bfr[ns] = ldsfrag(Bs, wc * 64 + ns * 16 + (l & 15), c16);
#pragma unroll
                for (int mi = 0; mi < 2; ++mi)
#pragma unroll
                    for (int ns = 0; ns < 4; ++ns)
                        acc[mi][ns] = __builtin_amdgcn_mfma_f32_16x16x32_bf16(af[mi], bfr[ns], acc[mi][ns], 0, 0, 0);
            }
            if (kc < 3) {
                asm volatile("s_waitcnt vmcnt(0) lgkmcnt(0)" ::: "memory");
                __builtin_amdgcn_s_barrier();
            }
        }

#pragma unroll
        for (int mi = 0; mi < 2; ++mi)
#pragma unroll
            for (int ns = 0; ns < 4; ++ns)
#pragma unroll
                for (int r = 0; r < 4; ++r) {
                    int m = ar0 + mi * 16 + (l >> 4) * 4 + r;
                    int n = nb0 + ns * 16 + (l & 15);
                    ob[(size_t)m * SS + n] = acc[mi][ns][r];
                }
    } else {
        const u16* qp = qpos + base;
        const u16* qn = qneg + base;
        const u16* kp = kpos + base;
        const u16* kn = kneg + base;
        u16* smqp = sm;
        u16* smqn = sm + 8192;
        u16* smkp = sm + 16384;
        u16* smkn = sm + 24576;

        int bamin = ti0 > 1 ? ti0 : 1;
        int bcmin = tj0 > 1 ? tj0 : 1;
        bool B2 = (ti1 > 0) && (tj1 > bamin);
        bool B3 = (tj1 > 0) && (ti1 > bcmin);

        // per-fragment need masks (bit = mi*4+ns), wave-uniform
        int fa[2], fb[2], fc[4], fd[4];
#pragma unroll
        for (int mi = 0; mi < 2; ++mi) {
            fa[mi] = tb[ar0 + mi * 16];
            fb[mi] = tb[ar0 + mi * 16 + 15];
        }
#pragma unroll
        for (int ns = 0; ns < 4; ++ns) {
            fc[ns] = tb[nb0 + ns * 16];
            fd[ns] = tb[nb0 + ns * 16 + 15];
        }
        u32 msk1 = 0, msk2 = 0, msk3 = 0;
#pragma unroll
        for (int mi = 0; mi < 2; ++mi)
#pragma unroll
            for (int ns = 0; ns < 4; ++ns) {
                u32 bit = 1u << (mi * 4 + ns);
                if ((fa[mi] == 0) | (fc[ns] == 0) | ((fa[mi] <= fd[ns]) & (fc[ns] <= fb[mi]))) msk1 |= bit;
                int amin = fa[mi] > 1 ? fa[mi] : 1;
                if ((fb[mi] > 0) & (fd[ns] > amin)) msk2 |= bit;
                int cmin = fc[ns] > 1 ? fc[ns] : 1;
                if ((fd[ns] > 0) & (fb[mi] > cmin)) msk3 |= bit;
            }
        msk1 = __builtin_amdgcn_readfirstlane(msk1);
        msk2 = __builtin_amdgcn_readfirstlane(msk2);
        msk3 = __builtin_amdgcn_readfirstlane(msk3);

        f32x4 a1[2][4] = {}, a2[2][4] = {}, a3[2][4] = {};
        for (int kc = 0; kc < 4; ++kc) {
            if (kc) __builtin_amdgcn_s_barrier();
            STAGE2(smqp, qp, m0, kc)
            if (B2) STAGE2(smqn, qn, m0, kc)
            STAGE2(smkp, kp, n0, kc)
            if (B3) STAGE2(smkn, kn, n0, kc)
            asm volatile("s_waitcnt vmcnt(0)" ::: "memory");
            __builtin_amdgcn_s_barrier();
#pragma unroll
            for (int ks = 0; ks < 2; ++ks) {
                int c16 = (l >> 4) + ks * 4;
                bf16x8 qpF[2], qnF[2], kpF[4], knF[4];
#pragma unroll
                for (int mi = 0; mi < 2; ++mi) {
                    int rr = wr * 32 + mi * 16 + (l & 15);
                    qpF[mi] = ldsfrag(smqp, rr, c16);
                    if (msk2) qnF[mi] = ldsfrag(smqn, rr, c16);
                }
#pragma unroll
                for (int ns = 0; ns < 4; ++ns) {
                    int rn = wc * 64 + ns * 16 + (l & 15);
                    kpF[ns] = ldsfrag(smkp, rn, c16);
                    if (msk3) knF[ns] = ldsfrag(smkn, rn, c16);
                }
#pragma unroll
                for (int mi = 0; mi < 2; ++mi)
#pragma unroll
                    for (int ns = 0; ns < 4; ++ns) {
                        u32 bit = 1u << (mi * 4 + ns);
                        if (msk1 & bit)
                            a1[mi][ns] = __builtin_amdgcn_mfma_f32_16x16x32_bf16(qpF[mi], kpF[ns], a1[mi][ns], 0, 0, 0);
                        if (msk2 & bit)
                            a2[mi][ns] = __builtin_amdgcn_mfma_f32_16x16x32_bf16(qnF[mi], kpF[ns], a2[mi][ns], 0, 0, 0);
                        if (msk3 & bit)
                            a3[mi][ns] = __builtin_amdgcn_mfma_f32_16x16x32_bf16(qpF[mi], knF[ns], a3[mi][ns], 0, 0, 0);
                    }
            }
        }

        int tj[4], ti_[2][4];
#pragma unroll
        for (int ns = 0; ns < 4; ++ns) tj[ns] = tb[nb0 + ns * 16 + (l & 15)];
#pragma unroll
        for (int mi = 0; mi < 2; ++mi)
#pragma unroll
            for (int r = 0; r < 4; ++r) ti_[mi][r] = tb[ar0 + mi * 16 + (l >> 4) * 4 + r];

#pragma unroll
        for (int mi = 0; mi < 2; ++mi)
#pragma unroll
            for (int ns = 0; ns < 4; ++ns)
#pragma unroll
                for (int r = 0; r < 4; ++r) {
                    int m = ar0 + mi * 16 + (l >> 4) * 4 + r;
                    int n = nb0 + ns * 16 + (l & 15);
                    int ti = ti_[mi][r], tjj = tj[ns];
                    float v = (ti > 0 && ti < tjj) ? a2[mi][ns][r]
                             : ((tjj > 0 && ti > tjj) ? a3[mi][ns][r] : a1[mi][ns][r]);
                    ob[(size_t)m * SS + n] = v;
                }
    }
}

extern "C" void kernel_launch(void* const* d_in, const int* in_sizes, int n_in,
                              void* d_out, int out_size, void* d_ws, size_t ws_size,
                              hipStream_t stream) {
    const float* x  = (const float*)d_in[0];
    const float* Wq = (const float*)d_in[1];
    const float* bq = (const float*)d_in[2];
    const float* Wk = (const float*)d_in[3];
    const float* bk = (const float*)d_in[4];
    const int* tok  = (const int*)d_in[5];
    const int* tid  = (const int*)d_in[6];
    float* out = (float*)d_out;

    char* ws = (char*)d_ws;
    const size_t MB = 1u << 20;
    u16* qpos = (u16*)(ws);
    u16* qneg = (u16*)(ws + 16 * MB);
    u16* kpos = (u16*)(ws + 32 * MB);
    u16* kneg = (u16*)(ws + 48 * MB);
    u16* xbf  = (u16*)(ws + 64 * MB);
    u16* Wt   = (u16*)(ws + 68 * MB);
    float2* trig = (float2*)(ws + 69 * MB);

    k0_castx<<<2048, 256, 0, stream>>>((const float4*)x, (u16x4*)xbf);
    dim3 tg(32, 4);
    k0_transw<<<tg, 256, 0, stream>>>(Wq, Wk, Wt);
    k0_trig<<<128, 256, 0, stream>>>(trig);
    k1_proj<<<1024, 512, 0, stream>>>(xbf, Wt, bq, bk, tok, trig, qpos, qneg, kpos, kneg);
    k2_gemm<<<2048, 512, 0, stream>>>(qpos, qneg, kpos, kneg, tid, out);
}

// Round 6
// 115.250 us; speedup vs baseline: 2.4551x; 1.0716x over previous
//
#include <hip/hip_runtime.h>

#define BB 8
#define SS 1024
#define HH 256
#define CC 4
#define NQ 1024  // H*C

typedef unsigned short u16;
typedef unsigned int u32;
typedef __attribute__((ext_vector_type(8))) __bf16 bf16x8;
typedef __attribute__((ext_vector_type(4))) float f32x4;
typedef __attribute__((ext_vector_type(4))) u32 u32x4;
typedef __attribute__((ext_vector_type(4))) u16 u16x4;

__device__ __forceinline__ u16 f2bf(float f) {
    u32 u = __float_as_uint(f);
    u32 r = (u + 0x7FFFu + ((u >> 16) & 1u)) >> 16;
    return (u16)r;
}

__device__ __forceinline__ void gld16(const u16* g, u16* l) {
    __builtin_amdgcn_global_load_lds(
        (const __attribute__((address_space(1))) void*)g,
        (__attribute__((address_space(3))) void*)l, 16, 0, 0);
}

// BK=64 tiles: [rows][64], 16B slot ^= (row & 7)
__device__ __forceinline__ bf16x8 ldsfrag(const u16* smem, int row, int c16) {
    const char* p = (const char*)smem + row * 128 + (((c16 ^ (row & 7)) & 7) << 4);
    return *(const bf16x8*)p;
}
// BK=32 tiles: [rows][32], 16B slot ^= ((row>>1) & 3)  (2-way residual = free)
__device__ __forceinline__ bf16x8 ldsfrag32(const u16* smem, int row, int c16) {
    const char* p = (const char*)smem + row * 64 + (((c16 ^ ((row >> 1) & 3)) & 3) << 4);
    return *(const bf16x8*)p;
}

#define WAITV(n) asm volatile("s_waitcnt vmcnt(" #n ")" ::: "memory")
#define WAITLG() asm volatile("s_waitcnt lgkmcnt(0)" ::: "memory")

// ---------- prep ----------
__global__ void k0_castx(const float4* __restrict__ x, u16x4* __restrict__ xbf) {
    int i = blockIdx.x * 256 + threadIdx.x;  // 524,288
    float4 v = x[i];
    u16x4 o = {f2bf(v.x), f2bf(v.y), f2bf(v.z), f2bf(v.w)};
    xbf[i] = o;
}

__global__ void k0_transw(const float* __restrict__ Wq, const float* __restrict__ Wk,
                          u16* __restrict__ Wt) {
    __shared__ u16 tl[64][65];
    int nb = blockIdx.x * 64, kb = blockIdx.y * 64;
    int c = threadIdx.x & 63;
#pragma unroll
    for (int r = threadIdx.x >> 6; r < 64; r += 4) {
        int k = kb + r, n = nb + c;
        float v = (n < NQ) ? Wq[k * NQ + n] : Wk[k * NQ + (n - NQ)];
        tl[c][r] = f2bf(v);
    }
    __syncthreads();
#pragma unroll
    for (int r = threadIdx.x >> 6; r < 64; r += 4) {
        Wt[(size_t)(nb + r) * HH + kb + c] = tl[r][c];
    }
}

__global__ void k0_trig(float2* __restrict__ trig) {
    int i = blockIdx.x * 256 + threadIdx.x;  // 32768
    int pos = i >> 7, f = i & 127;
    float freq = __expf(-(float)f * 0.07195578515529633f);
    float ang = (float)pos * freq;
    float s, c;
    sincosf(ang, &s, &c);
    trig[i] = make_float2(c, s);
}

// ---------- staging ----------
// BK=64 chunk [128][64], 512 thr, 2 gld16/thread, source-preswizzled
#define STAGE2(dst, srcbase, roff, kc)                                          \
    _Pragma("unroll") for (int i_ = 0; i_ < 2; ++i_) {                          \
        int r_ = ww * 16 + i_ * 8 + (l >> 3);                                   \
        int c16_ = (l & 7) ^ (r_ & 7);                                          \
        gld16((srcbase) + (size_t)((roff) + r_) * HH + (kc) * 64 + c16_ * 8,    \
              (dst) + (ww * 16 + i_ * 8) * 64);                                 \
    }
// BK=32 chunk [128][32], 512 thr, 1 gld16/thread
#define STAGE32(dst, srcbase, roff, kc) do {                                    \
        int r_ = ww * 4 + (l >> 2) + 0 * 0;                                     \
        r_ = (threadIdx.x >> 2);                                                \
        int sl_ = (threadIdx.x & 3) ^ ((r_ >> 1) & 3);                          \
        gld16((srcbase) + (size_t)((roff) + r_) * HH + (kc) * 32 + sl_ * 8,     \
              (dst) + ww * 512);                                                \
    } while (0)

// ---------- k1: projection + bias + RoPE (128x128, 512 thr, counted-vmcnt dbuf) ----------
__global__ void __launch_bounds__(512, 2) k1_proj(
    const u16* __restrict__ xbf, const u16* __restrict__ Wt,
    const float* __restrict__ bq, const float* __restrict__ bk,
    const int* __restrict__ tok, const float2* __restrict__ trig,
    u16* __restrict__ qpos, u16* __restrict__ qneg,
    u16* __restrict__ kpos, u16* __restrict__ kneg) {
    int h = blockIdx.x;                       // 1024 = 64 m x 16 n
    int logical = (h & 7) * 128 + (h >> 3);   // XCD-chunked
    int m0 = (logical >> 4) * 128, n0 = (logical & 15) * 128;
    int ww = threadIdx.x >> 6, l = threadIdx.x & 63;
    int wr = ww >> 1, wc = ww & 1;

    __shared__ u16 sm[32768];  // 64 KB
    u16* Ab[2] = {sm, sm + 16384};
    u16* Bb[2] = {sm + 8192, sm + 24576};

    f32x4 acc[2][4] = {};
    STAGE2(Ab[0], xbf, m0, 0)
    STAGE2(Bb[0], Wt, n0, 0)
    STAGE2(Ab[1], xbf, m0, 1)
    STAGE2(Bb[1], Wt, n0, 1)
    WAITV(4);
    __builtin_amdgcn_s_barrier();
#pragma unroll
    for (int kc = 0; kc < 4; ++kc) {
        const u16* As = Ab[kc & 1];
        const u16* Bs = Bb[kc & 1];
        __builtin_amdgcn_s_setprio(1);
#pragma unroll
        for (int ks = 0; ks < 2; ++ks) {
            int c16 = (l >> 4) + ks * 4;
            bf16x8 af[2], bfr[4];
#pragma unroll
            for (int mi = 0; mi < 2; ++mi) af[mi] = ldsfrag(As, wr * 32 + mi * 16 + (l & 15), c16);
#pragma unroll
            for (int ns = 0; ns < 4; ++ns) bfr[ns] = ldsfrag(Bs, wc * 64 + ns * 16 + (l & 15), c16);
#pragma unroll
            for (int mi = 0; mi < 2; ++mi)
#pragma unroll
                for (int ns = 0; ns < 4; ++ns)
                    acc[mi][ns] = __builtin_amdgcn_mfma_f32_16x16x32_bf16(af[mi], bfr[ns], acc[mi][ns], 0, 0, 0);
        }
        __builtin_amdgcn_s_setprio(0);
        if (kc < 3) {
            WAITLG();
            __builtin_amdgcn_s_barrier();       // release b[kc&1]
            if (kc < 2) {
                STAGE2(Ab[kc & 1], xbf, m0, kc + 2)
                STAGE2(Bb[kc & 1], Wt, n0, kc + 2)
                WAITV(4);
            } else {
                WAITV(0);
            }
            __builtin_amdgcn_s_barrier();       // b[(kc+1)&1] ready
        }
    }

#pragma unroll
    for (int mi = 0; mi < 2; ++mi)
#pragma unroll
        for (int ns = 0; ns < 4; ++ns) {
            int n = n0 + wc * 64 + ns * 16 + (l & 15);
            bool isq = n < NQ;
            int nc = n & (NQ - 1);
            float bias = isq ? bq[nc] : bk[nc];
            int c = nc >> 8, hh = nc & 255, fi = hh >> 1;
#pragma unroll
            for (int r = 0; r < 4; ++r) {
                int m = m0 + wr * 32 + mi * 16 + (l >> 4) * 4 + r;
                float val = acc[mi][ns][r] + bias;
                float other = __shfl_xor(val, 1);
                int pos = tok[m];
                float2 cs = trig[pos * 128 + fi];
                float rp, rn;
                if ((l & 1) == 0) {
                    rp = val * cs.x - other * cs.y;
                    rn = val * cs.x + other * cs.y;
                } else {
                    rp = other * cs.y + val * cs.x;
                    rn = -other * cs.y + val * cs.x;
                }
                int b = m >> 10, s = m & 1023;
                size_t oidx = ((size_t)((b << 2) | c) * SS + s) * HH + hh;
                if (isq) {
                    qpos[oidx] = f2bf(rp);
                    qneg[oidx] = f2bf(rn);
                } else {
                    kpos[oidx] = f2bf(rp);
                    kneg[oidx] = f2bf(rn);
                }
            }
        }
}

// ---------- k2: merged pure+mixed, 128x128, 512 thr, XCD-chunked, counted-vmcnt ----------
__global__ void __launch_bounds__(512, 2) k2_gemm(
    const u16* __restrict__ qpos, const u16* __restrict__ qneg,
    const u16* __restrict__ kpos, const u16* __restrict__ kneg,
    const int* __restrict__ thread_id, float* __restrict__ out) {
    int h = blockIdx.x;                        // 2048
    int logical = (h & 7) * 256 + (h >> 3);    // XCD x: bc 4x..4x+3 sequential
    int bc = logical >> 6;
    int t = logical & 63;
    int m0 = (t >> 3) * 128, n0 = (t & 7) * 128;
    const int* tb = thread_id + (bc >> 2) * SS;
    int ww = threadIdx.x >> 6, l = threadIdx.x & 63;
    int wr = ww >> 1, wc = ww & 1;
    int ti0 = tb[m0], ti1 = tb[m0 + 127], tj0 = tb[n0], tj1 = tb[n0 + 127];
    bool pure2 = (ti0 > 0) & (ti1 < tj0);
    bool pure3 = (tj0 > 0) & (ti0 > tj1);
    bool pure1 = (ti1 == 0) | (tj1 == 0) | ((ti0 == ti1) & (tj0 == tj1) & (ti0 == tj0));
    size_t base = (size_t)bc * (SS * HH);
    float* ob = out + (size_t)bc * ((size_t)SS * SS);
    int ar0 = m0 + wr * 32;
    int nb0 = n0 + wc * 64;

    __shared__ u16 sm[32768];  // 64 KB union

    if (pure1 | pure2 | pure3) {
        const u16* q = (pure2 ? qneg : qpos) + base;
        const u16* k = (pure3 ? kneg : kpos) + base;
        u16* Ab[2] = {sm, sm + 16384};
        u16* Bb[2] = {sm + 8192, sm + 24576};

        f32x4 acc[2][4] = {};
        STAGE2(Ab[0], q, m0, 0)
        STAGE2(Bb[0], k, n0, 0)
        STAGE2(Ab[1], q, m0, 1)
        STAGE2(Bb[1], k, n0, 1)
        WAITV(4);
        __builtin_amdgcn_s_barrier();
#pragma unroll
        for (int kc = 0; kc < 4; ++kc) {
            const u16* As = Ab[kc & 1];
            const u16* Bs = Bb[kc & 1];
            __builtin_amdgcn_s_setprio(1);
#pragma unroll
            for (int ks = 0; ks < 2; ++ks) {
                int c16 = (l >> 4) + ks * 4;
                bf16x8 af[2], bfr[4];
#pragma unroll
                for (int mi = 0; mi < 2; ++mi) af[mi] = ldsfrag(As, wr * 32 + mi * 16 + (l & 15), c16);
#pragma unroll
                for (int ns = 0; ns < 4; ++ns) bfr[ns] = ldsfrag(Bs, wc * 64 + ns * 16 + (l & 15), c16);
#pragma unroll
                for (int mi = 0; mi < 2; ++mi)
#pragma unroll
                    for (int ns = 0; ns < 4; ++ns)
                        acc[mi][ns] = __builtin_amdgcn_mfma_f32_16x16x32_bf16(af[mi], bfr[ns], acc[mi][ns], 0, 0, 0);
            }
            __builtin_amdgcn_s_setprio(0);
            if (kc < 3) {
                WAITLG();
                __builtin_amdgcn_s_barrier();
                if (kc < 2) {
                    STAGE2(Ab[kc & 1], q, m0, kc + 2)
                    STAGE2(Bb[kc & 1], k, n0, kc + 2)
                    WAITV(4);
                } else {
                    WAITV(0);
                }
                __builtin_amdgcn_s_barrier();
            }
        }

#pragma unroll
        for (int mi = 0; mi < 2; ++mi)
#pragma unroll
            for (int ns = 0; ns < 4; ++ns)
#pragma unroll
                for (int r = 0; r < 4; ++r) {
                    int m = ar0 + mi * 16 + (l >> 4) * 4 + r;
                    int n = nb0 + ns * 16 + (l & 15);
                    ob[(size_t)m * SS + n] = acc[mi][ns][r];
                }
    } else {
        // ---- mixed: BK=32 x 8 chunks, <=4 streams, counted-vmcnt dbuf ----
        const u16* qp = qpos + base;
        const u16* qn = qneg + base;
        const u16* kp = kpos + base;
        const u16* kn = kneg + base;
        // buffer bi (32 KB = 16384 elems): qp +0, qn +4096, kp +8192, kn +12288
        u16* bufb[2] = {sm, sm + 16384};

        int bamin = ti0 > 1 ? ti0 : 1;
        int bcmin = tj0 > 1 ? tj0 : 1;
        bool B2 = (ti1 > 0) && (tj1 > bamin);
        bool B3 = (tj1 > 0) && (ti1 > bcmin);

        int fa[2], fb[2], fc[4], fd[4];
#pragma unroll
        for (int mi = 0; mi < 2; ++mi) {
            fa[mi] = tb[ar0 + mi * 16];
            fb[mi] = tb[ar0 + mi * 16 + 15];
        }
#pragma unroll
        for (int ns = 0; ns < 4; ++ns) {
            fc[ns] = tb[nb0 + ns * 16];
            fd[ns] = tb[nb0 + ns * 16 + 15];
        }
        u32 msk1 = 0, msk2 = 0, msk3 = 0;
#pragma unroll
        for (int mi = 0; mi < 2; ++mi)
#pragma unroll
            for (int ns = 0; ns < 4; ++ns) {
                u32 bit = 1u << (mi * 4 + ns);
                if ((fa[mi] == 0) | (fc[ns] == 0) | ((fa[mi] <= fd[ns]) & (fc[ns] <= fb[mi]))) msk1 |= bit;
                int amin = fa[mi] > 1 ? fa[mi] : 1;
                if ((fb[mi] > 0) & (fd[ns] > amin)) msk2 |= bit;
                int cmin = fc[ns] > 1 ? fc[ns] : 1;
                if ((fd[ns] > 0) & (fb[mi] > cmin)) msk3 |= bit;
            }
        msk1 = __builtin_amdgcn_readfirstlane(msk1);
        msk2 = __builtin_amdgcn_readfirstlane(msk2);
        msk3 = __builtin_amdgcn_readfirstlane(msk3);

#define MSTAGE(bi, kc) do {                                \
        STAGE32(bufb[bi], qp, m0, kc);                     \
        if (B2) STAGE32(bufb[bi] + 4096, qn, m0, kc);      \
        STAGE32(bufb[bi] + 8192, kp, n0, kc);              \
        if (B3) STAGE32(bufb[bi] + 12288, kn, n0, kc);     \
    } while (0)
#define WAITN() do {                                       \
        if (B2 & B3) { WAITV(4); }                         \
        else if (B2 | B3) { WAITV(3); }                    \
        else { WAITV(2); }                                 \
    } while (0)

        f32x4 a1[2][4] = {}, a2[2][4] = {}, a3[2][4] = {};
        MSTAGE(0, 0);
        MSTAGE(1, 1);
        WAITN();
        __builtin_amdgcn_s_barrier();
#pragma unroll
        for (int kc = 0; kc < 8; ++kc) {
            const u16* bqp = bufb[kc & 1];
            const u16* bqn = bqp + 4096;
            const u16* bkp = bqp + 8192;
            const u16* bkn = bqp + 12288;
            int c16 = l >> 4;
            bf16x8 qpF[2], qnF[2], kpF[4], knF[4];
            __builtin_amdgcn_s_setprio(1);
#pragma unroll
            for (int mi = 0; mi < 2; ++mi) {
                int rr = wr * 32 + mi * 16 + (l & 15);
                qpF[mi] = ldsfrag32(bqp, rr, c16);
                if (msk2) qnF[mi] = ldsfrag32(bqn, rr, c16);
            }
#pragma unroll
            for (int ns = 0; ns < 4; ++ns) {
                int rn = wc * 64 + ns * 16 + (l & 15);
                kpF[ns] = ldsfrag32(bkp, rn, c16);
                if (msk3) knF[ns] = ldsfrag32(bkn, rn, c16);
            }
#pragma unroll
            for (int mi = 0; mi < 2; ++mi)
#pragma unroll
                for (int ns = 0; ns < 4; ++ns) {
                    u32 bit = 1u << (mi * 4 + ns);
                    if (msk1 & bit)
                        a1[mi][ns] = __builtin_amdgcn_mfma_f32_16x16x32_bf16(qpF[mi], kpF[ns], a1[mi][ns], 0, 0, 0);
                    if (msk2 & bit)
                        a2[mi][ns] = __builtin_amdgcn_mfma_f32_16x16x32_bf16(qnF[mi], kpF[ns], a2[mi][ns], 0, 0, 0);
                    if (msk3 & bit)
                        a3[mi][ns] = __builtin_amdgcn_mfma_f32_16x16x32_bf16(qpF[mi], knF[ns], a3[mi][ns], 0, 0, 0);
                }
            __builtin_amdgcn_s_setprio(0);
            if (kc < 7) {
                WAITLG();
                __builtin_amdgcn_s_barrier();   // release buf[kc&1]
                if (kc < 6) {
                    MSTAGE(kc & 1, kc + 2);
                    WAITN();
                } else {
                    WAITV(0);
                }
                __builtin_amdgcn_s_barrier();   // buf[(kc+1)&1] ready
            }
        }
#undef MSTAGE
#undef WAITN

        int tj[4], ti_[2][4];
#pragma unroll
        for (int ns = 0; ns < 4; ++ns) tj[ns] = tb[nb0 + ns * 16 + (l & 15)];
#pragma unroll
        for (int mi = 0; mi < 2; ++mi)
#pragma unroll
            for (int r = 0; r < 4; ++r) ti_[mi][r] = tb[ar0 + mi * 16 + (l >> 4) * 4 + r];

#pragma unroll
        for (int mi = 0; mi < 2; ++mi)
#pragma unroll
            for (int ns = 0; ns < 4; ++ns)
#pragma unroll
                for (int r = 0; r < 4; ++r) {
                    int m = ar0 + mi * 16 + (l >> 4) * 4 + r;
                    int n = nb0 + ns * 16 + (l & 15);
                    int ti = ti_[mi][r], tjj = tj[ns];
                    float v = (ti > 0 && ti < tjj) ? a2[mi][ns][r]
                             : ((tjj > 0 && ti > tjj) ? a3[mi][ns][r] : a1[mi][ns][r]);
                    ob[(size_t)m * SS + n] = v;
                }
    }
}

extern "C" void kernel_launch(void* const* d_in, const int* in_sizes, int n_in,
                              void* d_out, int out_size, void* d_ws, size_t ws_size,
                              hipStream_t stream) {
    const float* x  = (const float*)d_in[0];
    const float* Wq = (const float*)d_in[1];
    const float* bq = (const float*)d_in[2];
    const float* Wk = (const float*)d_in[3];
    const float* bk = (const float*)d_in[4];
    const int* tok  = (const int*)d_in[5];
    const int* tid  = (const int*)d_in[6];
    float* out = (float*)d_out;

    char* ws = (char*)d_ws;
    const size_t MB = 1u << 20;
    u16* qpos = (u16*)(ws);
    u16* qneg = (u16*)(ws + 16 * MB);
    u16* kpos = (u16*)(ws + 32 * MB);
    u16* kneg = (u16*)(ws + 48 * MB);
    u16* xbf  = (u16*)(ws + 64 * MB);
    u16* Wt   = (u16*)(ws + 68 * MB);
    float2* trig = (float2*)(ws + 69 * MB);

    k0_castx<<<2048, 256, 0, stream>>>((const float4*)x, (u16x4*)xbf);
    dim3 tg(32, 4);
    k0_transw<<<tg, 256, 0, stream>>>(Wq, Wk, Wt);
    k0_trig<<<128, 256, 0, stream>>>(trig);
    k1_proj<<<1024, 512, 0, stream>>>(xbf, Wt, bq, bk, tok, trig, qpos, qneg, kpos, kneg);
    k2_gemm<<<2048, 512, 0, stream>>>(qpos, qneg, kpos, kneg, tid, out);
}